// Round 1
// baseline (160.034 us; speedup 1.0000x reference)
//
#include <hip/hip_runtime.h>
#include <math.h>

#define N_ROWS 8192
#define N_NEG 16

__device__ __forceinline__ float log_sigmoid(float v) {
    // log(sigmoid(v)) = min(v,0) - log1p(exp(-|v|))  (numerically stable)
    return fminf(v, 0.0f) - log1pf(__expf(-fabsf(v)));
}

// One wave (64 lanes) per row. Maintains a wave-uniform replicated top-16
// list of masked scores; threshold tau = current 16th largest gates the
// expensive insert path (expected ~116 inserts per 8192-element row).
__global__ __launch_bounds__(256) void nsl_topk_kernel(
        const float* __restrict__ x,
        const int*   __restrict__ sel,
        float*       __restrict__ out) {
    const int lane = threadIdx.x & 63;
    const int wid  = threadIdx.x >> 6;
    const int row  = (blockIdx.x << 2) + wid;   // 4 waves per 256-thread block

    const int seli = sel[row];
    const float* xrow = x + (size_t)row * N_ROWS;

    // replicated (wave-uniform) sorted-descending top-16
    float top[16];
#pragma unroll
    for (int k = 0; k < 16; ++k) top[k] = -3.0e38f;
    float tau = -3.0e38f;

    // 8192 cols / (64 lanes * 4 per lane) = 32 iterations
#pragma unroll 1
    for (int it = 0; it < N_ROWS / (64 * 4); ++it) {
        const int c0 = (it * 64 + lane) * 4;
        const float4 v4 = *reinterpret_cast<const float4*>(xrow + c0);
        const int4   s4 = *reinterpret_cast<const int4*>(sel + c0);

        float m[4];
        m[0] = (s4.x != seli) ? v4.x : 0.0f;
        m[1] = (s4.y != seli) ? v4.y : 0.0f;
        m[2] = (s4.z != seli) ? v4.z : 0.0f;
        m[3] = (s4.w != seli) ? v4.w : 0.0f;

        const float mx = fmaxf(fmaxf(m[0], m[1]), fmaxf(m[2], m[3]));
        if (__any(mx > tau)) {
#pragma unroll
            for (int k = 0; k < 4; ++k) {
                unsigned long long ball = __ballot(m[k] > tau);
                while (ball) {
                    const int src = __ffsll(ball) - 1;
                    ball &= (ball - 1);
                    const float cand = __shfl(m[k], src);
                    if (cand > tau) {   // wave-uniform (cand, tau both uniform)
                        // bubble-insert: keeps list sorted descending, drops old min
                        float cur = cand;
#pragma unroll
                        for (int j = 0; j < 16; ++j) {
                            const float o = top[j];
                            top[j] = fmaxf(o, cur);
                            cur    = fminf(o, cur);
                        }
                        tau = top[15];
                    }
                }
            }
        }
    }

    if (lane == 0) {
        float negsum = 0.0f;
#pragma unroll
        for (int k = 0; k < 16; ++k) negsum += log_sigmoid(-top[k]);
        const float d = xrow[row];                       // raw diagonal score
        const float contrib =
            -log_sigmoid(d) * (1.0f / (float)N_ROWS)
            - negsum * (1.0f / ((float)N_ROWS * (float)N_NEG));
        atomicAdd(out, contrib);
    }
}

extern "C" void kernel_launch(void* const* d_in, const int* in_sizes, int n_in,
                              void* d_out, int out_size, void* d_ws, size_t ws_size,
                              hipStream_t stream) {
    const float* x   = (const float*)d_in[0];
    const int*   sel = (const int*)d_in[1];
    float* out = (float*)d_out;

    // d_out is poisoned once before timing and NOT re-zeroed between replays.
    hipMemsetAsync(out, 0, sizeof(float) * out_size, stream);

    // one wave per row, 4 waves per block
    dim3 grid(N_ROWS / 4), block(256);
    nsl_topk_kernel<<<grid, block, 0, stream>>>(x, sel, out);
}

// Round 2
// 151.124 us; speedup vs baseline: 1.0590x; 1.0590x over previous
//
#include <hip/hip_runtime.h>
#include <math.h>

#define N_ROWS 8192
#define N_NEG 16
#define CHUNK 512                    // 64 lanes * 8 elems
#define NCHUNK (N_ROWS / CHUNK)      // 16

__device__ __forceinline__ float log_sigmoid(float v) {
    // log(sigmoid(v)) = min(v,0) - log1p(exp(-|v|))  (numerically stable)
    return fminf(v, 0.0f) - log1pf(__expf(-fabsf(v)));
}

// One wave per row. Top-16 is DISTRIBUTED across lanes 0..15 (sorted
// descending, one value per lane); tau = 16th value, wave-uniform.
// Fast path scans RAW values only (valid gate once tau >= 0, since the
// mask can only replace a value with 0). Slow path masks + inserts.
__global__ __launch_bounds__(256) void nsl_topk_kernel(
        const float* __restrict__ x,
        const int*   __restrict__ sel,
        float*       __restrict__ out) {
    const int lane = threadIdx.x & 63;
    const int wid  = threadIdx.x >> 6;
    const int row  = (blockIdx.x << 2) + wid;   // 4 waves / 256-thr block

    const int seli = sel[row];
    const float* xrow = x + (size_t)row * N_ROWS;

    float t   = -3.0e38f;   // this lane's slot of the distributed top-16
    float tau = -3.0e38f;   // current 16th-largest (uniform)

    const float* pA = xrow + lane * 4;
    // prefetch chunk 0: lane reads [lane*4 .. lane*4+3] and [+256 ..]
    float4 a0 = *reinterpret_cast<const float4*>(pA);
    float4 a1 = *reinterpret_cast<const float4*>(pA + 256);

#pragma unroll 1
    for (int it = 0; it < NCHUNK; ++it) {
        const float4 c0 = a0, c1 = a1;
        // unconditional prefetch of next chunk (wraps to 0 on last iter;
        // redundant L2-hit load, keeps loads hoistable above the branch)
        const int nx = (it + 1) & (NCHUNK - 1);
        a0 = *reinterpret_cast<const float4*>(pA + nx * CHUNK);
        a1 = *reinterpret_cast<const float4*>(pA + nx * CHUNK + 256);

        const float mx = fmaxf(fmaxf(fmaxf(c0.x, c0.y), fmaxf(c0.z, c0.w)),
                               fmaxf(fmaxf(c1.x, c1.y), fmaxf(c1.z, c1.w)));
        const bool anyhit = __any(mx > tau);
        if (anyhit || tau < 0.0f) {
            // ---- slow path: mask, then exact serialized inserts ----
            const int cb = it * CHUNK;
            const int4 s0 = *reinterpret_cast<const int4*>(sel + cb + lane * 4);
            const int4 s1 = *reinterpret_cast<const int4*>(sel + cb + 256 + lane * 4);
            float m[8];
            m[0] = (s0.x != seli) ? c0.x : 0.0f;
            m[1] = (s0.y != seli) ? c0.y : 0.0f;
            m[2] = (s0.z != seli) ? c0.z : 0.0f;
            m[3] = (s0.w != seli) ? c0.w : 0.0f;
            m[4] = (s1.x != seli) ? c1.x : 0.0f;
            m[5] = (s1.y != seli) ? c1.y : 0.0f;
            m[6] = (s1.z != seli) ? c1.z : 0.0f;
            m[7] = (s1.w != seli) ? c1.w : 0.0f;
#pragma unroll
            for (int k = 0; k < 8; ++k) {
                unsigned long long ball = __ballot(m[k] > tau);
                while (ball) {
                    const int src = __ffsll(ball) - 1;
                    const float cand = __shfl(m[k], src);
                    ball &= (ball - 1);                 // drop processed lane
                    if (cand > tau) {
                        // distributed sorted insert (lanes 0..15 meaningful)
                        float tprev = __shfl_up(t, 1);
                        if (lane == 0) tprev = 3.0e38f; // sentinel
                        t = (t >= cand) ? t : (tprev >= cand ? cand : tprev);
                        tau = __shfl(t, 15);
                        ball &= __ballot(m[k] > tau);   // prune vs new tau
                    }
                }
            }
        }
    }

    // negsum = sum over the 16 kept values of log_sigmoid(-v)
    float ls = (lane < 16) ? log_sigmoid(-t) : 0.0f;
    ls += __shfl_xor(ls, 8);
    ls += __shfl_xor(ls, 4);
    ls += __shfl_xor(ls, 2);
    ls += __shfl_xor(ls, 1);

    if (lane == 0) {
        const float d = xrow[row];                      // raw diagonal score
        const float contrib =
            -log_sigmoid(d) * (1.0f / (float)N_ROWS)
            - ls * (1.0f / ((float)N_ROWS * (float)N_NEG));
        atomicAdd(out, contrib);
    }
}

extern "C" void kernel_launch(void* const* d_in, const int* in_sizes, int n_in,
                              void* d_out, int out_size, void* d_ws, size_t ws_size,
                              hipStream_t stream) {
    const float* x   = (const float*)d_in[0];
    const int*   sel = (const int*)d_in[1];
    float* out = (float*)d_out;

    // d_out is poisoned once and NOT re-zeroed between replays.
    hipMemsetAsync(out, 0, sizeof(float) * out_size, stream);

    dim3 grid(N_ROWS / 4), block(256);
    nsl_topk_kernel<<<grid, block, 0, stream>>>(x, sel, out);
}

// Round 3
// 73.165 us; speedup vs baseline: 2.1873x; 2.0655x over previous
//
#include <hip/hip_runtime.h>
#include <math.h>

#define N_ROWS 8192
#define N_NEG 16

__device__ __forceinline__ float log_sigmoid(float v) {
    // log(sigmoid(v)) = min(v,0) - log1p(exp(-|v|))  (numerically stable)
    return fminf(v, 0.0f) - log1pf(__expf(-fabsf(v)));
}

// Distributed top-16 insert: lanes 0..15 hold the sorted-descending list.
// cand and tau are wave-uniform. ~10 VALU ops per insert.
#define INSERT(mv)                                                          \
    {                                                                       \
        unsigned long long ball = __ballot((mv) > tau);                     \
        while (ball) {                                                      \
            const int src = __ffsll((unsigned long long)ball) - 1;          \
            const float cand = __shfl((mv), src);                           \
            ball &= ball - 1;                                               \
            if (cand > tau) {                                               \
                float tprev = __shfl_up(t, 1);                              \
                if (lane == 0) tprev = 3.0e38f;                             \
                t = (t >= cand) ? t : (tprev >= cand ? cand : tprev);       \
                tau = __shfl(t, 15);                                        \
                ball &= __ballot((mv) > tau); /* prune vs new tau */        \
            }                                                               \
        }                                                                   \
    }

// 8 waves per block, one row per wave. sel staged in LDS (slow path never
// touches vmcnt). Register ping-pong prefetch, depth 4 chunks (1 KB each).
// One atomicAdd per BLOCK (1024 total) instead of per row (8192).
__global__ __launch_bounds__(512) void nsl_topk_kernel(
        const float* __restrict__ x,
        const int*   __restrict__ sel,
        float*       __restrict__ out) {
    __shared__ int   sel_lds[N_ROWS];
    __shared__ float partial[8];

    // cooperative stage of the full sel vector (32 KB), coalesced int4
    {
        const int4* s4 = reinterpret_cast<const int4*>(sel);
        int4*       d4 = reinterpret_cast<int4*>(sel_lds);
#pragma unroll
        for (int k = 0; k < 4; ++k)
            d4[k * 512 + threadIdx.x] = s4[k * 512 + threadIdx.x];
    }
    __syncthreads();

    const int lane = threadIdx.x & 63;
    const int wid  = threadIdx.x >> 6;
    const int row  = (blockIdx.x << 3) + wid;

    const int    seli = sel_lds[row];
    const float* xrow = x + (size_t)row * N_ROWS;
    const float* pw   = xrow + lane * 4;

    float t   = -3.0e38f;   // this lane's slot of the distributed top-16
    float tau = -3.0e38f;   // current 16th-largest (uniform)

    // chunk c = floats [c*256, c*256+255]; lane owns 4 of them. 32 chunks.
    float4 buf[4];
#pragma unroll
    for (int j = 0; j < 4; ++j)
        buf[j] = *reinterpret_cast<const float4*>(pw + j * 256);

#pragma unroll 1
    for (int g = 0; g < 8; ++g) {
#pragma unroll
        for (int j = 0; j < 4; ++j) {
            const int c = (g << 2) + j;
            const float4 v = buf[j];
            // replace immediately: keeps ~4 loads in flight, static index j
            buf[j] = *reinterpret_cast<const float4*>(pw + ((c + 4) & 31) * 256);

            const float mxv = fmaxf(fmaxf(v.x, v.y), fmaxf(v.z, v.w));
            // exact gate: once tau>=0, raw>tau <=> masked>tau (mask only
            // writes 0). While tau<0 the gate is trivially true -> exact.
            if (__any(mxv > tau)) {
                const int4 s = *reinterpret_cast<const int4*>(
                    &sel_lds[(c << 8) + (lane << 2)]);
                const float m0 = (s.x != seli) ? v.x : 0.0f;
                const float m1 = (s.y != seli) ? v.y : 0.0f;
                const float m2 = (s.z != seli) ? v.z : 0.0f;
                const float m3 = (s.w != seli) ? v.w : 0.0f;
                INSERT(m0);
                INSERT(m1);
                INSERT(m2);
                INSERT(m3);
            }
        }
    }

    // negsum over the 16 kept values (lanes 0..15), xor-reduce in-group
    float ls = (lane < 16) ? log_sigmoid(-t) : 0.0f;
    ls += __shfl_xor(ls, 8);
    ls += __shfl_xor(ls, 4);
    ls += __shfl_xor(ls, 2);
    ls += __shfl_xor(ls, 1);

    if (lane == 0) {
        const float d = xrow[row];                      // raw diagonal score
        partial[wid] = -log_sigmoid(d) * (1.0f / (float)N_ROWS)
                       - ls * (1.0f / ((float)N_ROWS * (float)N_NEG));
    }
    __syncthreads();

    if (threadIdx.x == 0) {
        float s = 0.0f;
#pragma unroll
        for (int w = 0; w < 8; ++w) s += partial[w];
        atomicAdd(out, s);                               // 1 per block
    }
}

extern "C" void kernel_launch(void* const* d_in, const int* in_sizes, int n_in,
                              void* d_out, int out_size, void* d_ws, size_t ws_size,
                              hipStream_t stream) {
    const float* x   = (const float*)d_in[0];
    const int*   sel = (const int*)d_in[1];
    float* out = (float*)d_out;

    // d_out is poisoned once and NOT re-zeroed between replays.
    hipMemsetAsync(out, 0, sizeof(float) * out_size, stream);

    dim3 grid(N_ROWS / 8), block(512);
    nsl_topk_kernel<<<grid, block, 0, stream>>>(x, sel, out);
}

// Round 4
// 65.045 us; speedup vs baseline: 2.4604x; 1.1248x over previous
//
#include <hip/hip_runtime.h>
#include <math.h>

#define N_ROWS 8192
#define N_NEG 16
#define NBLK (N_ROWS / 8)   // 1024 main-kernel blocks

__device__ __forceinline__ float log_sigmoid(float v) {
    // log(sigmoid(v)) = min(v,0) - log1p(exp(-|v|))  (numerically stable)
    return fminf(v, 0.0f) - log1pf(__expf(-fabsf(v)));
}

// Distributed top-16 insert: lanes 0..15 hold the sorted-descending list.
// cand and tau are wave-uniform. ~10 VALU ops per insert.
#define INSERT(mv)                                                          \
    {                                                                       \
        unsigned long long ball = __ballot((mv) > tau);                     \
        while (ball) {                                                      \
            const int src = __ffsll((unsigned long long)ball) - 1;          \
            const float cand = __shfl((mv), src);                           \
            ball &= ball - 1;                                               \
            if (cand > tau) {                                               \
                float tprev = __shfl_up(t, 1);                              \
                if (lane == 0) tprev = 3.0e38f;                             \
                t = (t >= cand) ? t : (tprev >= cand ? cand : tprev);       \
                tau = __shfl(t, 15);                                        \
                ball &= __ballot((mv) > tau); /* prune vs new tau */        \
            }                                                               \
        }                                                                   \
    }

// 8 waves per block, one row per wave. sel staged in LDS. Register
// ping-pong prefetch depth 4. NO atomics: per-block partial to d_ws.
__global__ __launch_bounds__(512) void nsl_topk_kernel(
        const float* __restrict__ x,
        const int*   __restrict__ sel,
        float*       __restrict__ ws) {
    __shared__ int   sel_lds[N_ROWS];
    __shared__ float partial[8];

    // cooperative stage of the full sel vector (32 KB), coalesced int4
    {
        const int4* s4 = reinterpret_cast<const int4*>(sel);
        int4*       d4 = reinterpret_cast<int4*>(sel_lds);
#pragma unroll
        for (int k = 0; k < 4; ++k)
            d4[k * 512 + threadIdx.x] = s4[k * 512 + threadIdx.x];
    }
    __syncthreads();

    const int lane = threadIdx.x & 63;
    const int wid  = threadIdx.x >> 6;
    const int row  = (blockIdx.x << 3) + wid;

    const int    seli = sel_lds[row];
    const float* xrow = x + (size_t)row * N_ROWS;
    const float* pw   = xrow + lane * 4;

    float t   = -3.0e38f;   // this lane's slot of the distributed top-16
    float tau = -3.0e38f;   // current 16th-largest (uniform)

    // chunk c = floats [c*256 .. c*256+255]; lane owns 4. 32 chunks total.
    float4 buf[4];
#pragma unroll
    for (int j = 0; j < 4; ++j)
        buf[j] = *reinterpret_cast<const float4*>(pw + j * 256);

#define BODY(c, PREFETCH)                                                   \
    {                                                                       \
        const float4 v = buf[(c) & 3];                                      \
        if (PREFETCH)                                                       \
            buf[(c) & 3] =                                                  \
                *reinterpret_cast<const float4*>(pw + ((c) + 4) * 256);     \
        const float mxv = fmaxf(fmaxf(v.x, v.y), fmaxf(v.z, v.w));          \
        /* exact gate: once tau>=0, raw>tau <=> masked>tau */               \
        if (__any(mxv > tau)) {                                             \
            const int4 s = *reinterpret_cast<const int4*>(                  \
                &sel_lds[((c) << 8) + (lane << 2)]);                        \
            const float m0 = (s.x != seli) ? v.x : 0.0f;                    \
            const float m1 = (s.y != seli) ? v.y : 0.0f;                    \
            const float m2 = (s.z != seli) ? v.z : 0.0f;                    \
            const float m3 = (s.w != seli) ? v.w : 0.0f;                    \
            INSERT(m0);                                                     \
            INSERT(m1);                                                     \
            INSERT(m2);                                                     \
            INSERT(m3);                                                     \
        }                                                                   \
    }

#pragma unroll 1
    for (int g = 0; g < 7; ++g) {   // chunks 0..27 with prefetch
#pragma unroll
        for (int j = 0; j < 4; ++j) BODY((g << 2) + j, true);
    }
#pragma unroll
    for (int j = 0; j < 4; ++j) BODY(28 + j, false);  // tail, no prefetch
#undef BODY

    // negsum over the 16 kept values (lanes 0..15), xor-reduce in-group
    float ls = (lane < 16) ? log_sigmoid(-t) : 0.0f;
    ls += __shfl_xor(ls, 8);
    ls += __shfl_xor(ls, 4);
    ls += __shfl_xor(ls, 2);
    ls += __shfl_xor(ls, 1);

    if (lane == 0) {
        const float d = xrow[row];                      // raw diagonal score
        partial[wid] = -log_sigmoid(d) * (1.0f / (float)N_ROWS)
                       - ls * (1.0f / ((float)N_ROWS * (float)N_NEG));
    }
    __syncthreads();

    if (threadIdx.x == 0) {
        float s = 0.0f;
#pragma unroll
        for (int w = 0; w < 8; ++w) s += partial[w];
        ws[blockIdx.x] = s;                             // plain store, no atomic
    }
}

// single-block final reduce: 1024 partials -> d_out[0]
__global__ __launch_bounds__(256) void nsl_reduce_kernel(
        const float* __restrict__ ws, float* __restrict__ out) {
    __shared__ float red[4];
    float s = 0.0f;
#pragma unroll
    for (int k = 0; k < NBLK / 256; ++k) s += ws[k * 256 + threadIdx.x];
    s += __shfl_xor(s, 32);
    s += __shfl_xor(s, 16);
    s += __shfl_xor(s, 8);
    s += __shfl_xor(s, 4);
    s += __shfl_xor(s, 2);
    s += __shfl_xor(s, 1);
    const int lane = threadIdx.x & 63, wid = threadIdx.x >> 6;
    if (lane == 0) red[wid] = s;
    __syncthreads();
    if (threadIdx.x == 0)
        out[0] = red[0] + red[1] + red[2] + red[3];
}

extern "C" void kernel_launch(void* const* d_in, const int* in_sizes, int n_in,
                              void* d_out, int out_size, void* d_ws, size_t ws_size,
                              hipStream_t stream) {
    const float* x   = (const float*)d_in[0];
    const int*   sel = (const int*)d_in[1];
    float* out = (float*)d_out;
    float* ws  = (float*)d_ws;

    nsl_topk_kernel<<<dim3(NBLK), dim3(512), 0, stream>>>(x, sel, ws);
    nsl_reduce_kernel<<<dim3(1), dim3(256), 0, stream>>>(ws, out);
}